// Round 9
// baseline (518.897 us; speedup 1.0000x reference)
//
#include <hip/hip_runtime.h>

// LSTMModel: 4-layer LSTM (H=50, IN=7, B=1024, T=512) + FC(50->25 relu ->1).
// R9 = R8 + PHASE STAGGERING. R8's counters showed VALU-busy and MFMA-busy
// SUM per tick (single barrier locks all waves into the same phase). Split
// each tick into two barriered windows: even layers (0,2) MFMA in window A,
// update in window B; odd layers (1,3) the opposite. Each SIMD holds one wave
// per layer -> every window has 2 MFMA waves + 2 VALU waves per SIMD, so the
// matrix and VALU pipes overlap (m114). Gates persist in acc regs across the
// intra-tick barrier.
// Schedule: h_l(t) stored to slot t&1 during layer l's update window.
// Fill offsets F = {0,2,3,5}: at iteration i, even layer does MFMA(t=i-F) in
// part1 and update(t) in part2; odd layer does update(t_u=i-F) in part1 and
// MFMA(t_u+1) in part2. All producer->consumer pairs are >=1 barrier apart.
// Layout (R8): Xpack[2][4][80] row = [x(t) 0..6 | 1.0 at 7 | h0 at 8..57],
// x(t) lives at slot (t-1)&1 alongside h0(t-1) (L0 reads one combined row);
// L1 reads the same rows as input (A: k7->bias, k8..57->Wih1). Hbuf[3] for
// h1..h3; Xstage raw-x ring refilled in bursts.

#define H 50
#define INSZ 7
#define TT 512
#define NL 4
#define FC1N 25
#define BPG 4
#define NBLK 256
#define NTHREADS 1024
#define HS 80        // row stride in halves (40 dw = 8 mod 32: <=2-way, free)
#define BIASL 56

typedef _Float16 half_t;
typedef __attribute__((ext_vector_type(8))) _Float16 half8_t;
typedef __attribute__((ext_vector_type(4))) float float4_t;

struct Params {
  const float* x;
  const float* Wih[NL];
  const float* Whh[NL];
  const float* bih[NL];
  const float* bhh[NL];
  const float* W1;
  const float* b1;
  const float* W2;
  const float* b2;
  float* out;
};

#define MFMA16(A, B, C) __builtin_amdgcn_mfma_f32_16x16x32_f16((A), (B), (C), 0, 0, 0)
#define EXP2F(x) __builtin_amdgcn_exp2f(x)
#define RCPF(x) __builtin_amdgcn_rcpf(x)

__global__ __launch_bounds__(NTHREADS, 4) void lstm_r9(Params p) {
  __shared__ __align__(16) half_t Xpack[2][BPG][HS];     // L0 B-row / L1 input
  __shared__ __align__(16) half_t Hbuf[3][2][BPG][HS];   // own-h L1..L3
  __shared__ __align__(16) half_t Xstage[64][BPG][8];    // raw-x ring
  __shared__ float fc_h[BPG][H];
  __shared__ float fc1_buf[BPG][FC1N];

  const int tid = threadIdx.x;
  const int b0 = blockIdx.x * BPG;
  const int lane = tid & 63;
  const int quad = lane >> 4;
  const int col = lane & 15;
  const int glay = tid >> 8;                     // layer (4 waves each)
  const int wl = (((tid >> 6) & 3) + glay) & 3;  // M-chunk, SIMD-balanced

  // ---- A fragments (same maps as R8) ----
  half8_t afrag[4][4];
#pragma unroll
  for (int t4 = 0; t4 < 4; ++t4) {
#pragma unroll
    for (int g = 0; g < 4; ++g) {
      half8_t v;
#pragma unroll
      for (int j = 0; j < 8; ++j) {
        const int r = wl * 64 + t4 * 16 + col;
        const int u = r >> 2, q = r & 3;
        const int k = g * 32 + quad * 8 + j;
        float wv = 0.0f;
        if (u < H) {
          const int row = q * H + u;
          if (glay == 0) {           // K=64: x 0..6, bias 7, own-h 8..57
            if (k < INSZ) wv = p.Wih[0][row * INSZ + k];
            else if (k == 7) wv = p.bih[0][row] + p.bhh[0][row];
            else if (k >= 8 && k < 8 + H) wv = p.Whh[0][row * H + (k - 8)];
          } else if (glay == 1) {    // input from Xpack: bias 7, in-h 8..57
            if (k == 7) wv = p.bih[1][row] + p.bhh[1][row];
            else if (k >= 8 && k < 8 + H) wv = p.Wih[1][row * H + (k - 8)];
            else if (k >= 64 && k < 64 + H) wv = p.Whh[1][row * H + (k - 64)];
          } else {                   // in-h 0..49, bias 56, own-h 64..113
            if (k < H) wv = p.Wih[glay][row * H + k];
            else if (k == BIASL) wv = p.bih[glay][row] + p.bhh[glay][row];
            else if (k >= 64 && k < 64 + H) wv = p.Whh[glay][row * H + (k - 64)];
          }
        }
        v[j] = (half_t)wv;
      }
      afrag[t4][g] = v;
    }
  }

  // ---- init LDS ----
  {
    unsigned* xz = (unsigned*)Xpack;
    for (int i = tid; i < 2 * BPG * HS / 2; i += NTHREADS) xz[i] = 0u;
    unsigned* hz = (unsigned*)Hbuf;
    for (int i = tid; i < 3 * 2 * BPG * HS / 2; i += NTHREADS) hz[i] = 0u;
  }
  __syncthreads();
  if (tid < 8) {  // Xpack bias-1.0 at slot 7, both parities
    Xpack[tid >> 2][tid & 3][7] = (half_t)1.0f;
  } else if (tid < 8 + 24) {  // Hbuf const-1.0 at slot 56
    const int i = tid - 8, l = i >> 3, pr = (i >> 2) & 1, b = i & 3;
    Hbuf[l][pr][b][BIASL] = (half_t)1.0f;
  }
  // ring fill t=0..63; x(0) -> Xpack[1] (x(t) lives at slot (t-1)&1)
  for (int i = tid; i < 64 * BPG * INSZ; i += NTHREADS) {
    const int t = i / (BPG * INSZ), rem = i % (BPG * INSZ);
    const int b = rem / INSZ, k = rem % INSZ;
    const half_t xh = (half_t)p.x[((size_t)(b0 + b) * TT + t) * INSZ + k];
    Xstage[t][b][k] = xh;
    if (t == 0) Xpack[1][b][k] = xh;
  }
  __syncthreads();

  // ---- per-lane roles ----
  const int bb = col & 3;
  const int tsel = col >> 2;
  const int uu = 16 * wl + 4 * tsel + quad;
  const bool updact = (uu < H);
  const bool evl = (glay & 1) == 0;
  const int F = glay + ((glay + 1) >> 1);  // 0,2,3,5
  const int fpar = F & 1;

  // slot-q pointers: in_rd[q] = input B-row at slot q; own_rd[q] = own row;
  // st[q] = h store. L0: own_rd = Xpack combined row (M_PHASE uses POWN only).
  const half_t* in_rd[2];
  const half_t* own_rd[2];
  half_t* st[2];
  if (glay == 0) {
    own_rd[0] = &Xpack[0][bb][quad * 8];
    own_rd[1] = &Xpack[1][bb][quad * 8];
    in_rd[0] = own_rd[0];  // unused
    in_rd[1] = own_rd[1];
    st[0] = &Xpack[0][bb][8 + uu];
    st[1] = &Xpack[1][bb][8 + uu];
  } else if (glay == 1) {
    in_rd[0] = &Xpack[0][bb][quad * 8];
    in_rd[1] = &Xpack[1][bb][quad * 8];
    own_rd[0] = &Hbuf[0][0][bb][quad * 8];
    own_rd[1] = &Hbuf[0][1][bb][quad * 8];
    st[0] = &Hbuf[0][0][bb][uu];
    st[1] = &Hbuf[0][1][bb][uu];
  } else {
    in_rd[0] = &Hbuf[glay - 2][0][bb][quad * 8];
    in_rd[1] = &Hbuf[glay - 2][1][bb][quad * 8];
    own_rd[0] = &Hbuf[glay - 1][0][bb][quad * 8];
    own_rd[1] = &Hbuf[glay - 1][1][bb][quad * 8];
    st[0] = &Hbuf[glay - 1][0][bb][uu];
    st[1] = &Hbuf[glay - 1][1][bb][uu];
  }
  // hoisted per-iteration-parity pointers. PAR(i) = (i&1)^fpar = t&1.
  // even-i (PAR = fpar):
  const half_t* A_m_in = in_rd[fpar];          // even-layer MFMA input (slot t&1)
  const half_t* A_m_own = own_rd[fpar ^ 1];    // own at (t-1)&1
  half_t* A_st = st[fpar];                     // update store (both roles)
  const half_t* A_mo_in = in_rd[fpar ^ 1];     // odd-layer MFMA (t_m = t_u+1)
  const half_t* A_mo_own = own_rd[fpar];
  // odd-i:
  const half_t* B_m_in = in_rd[fpar ^ 1];
  const half_t* B_m_own = own_rd[fpar];
  half_t* B_st = st[fpar ^ 1];
  const half_t* B_mo_in = in_rd[fpar];
  const half_t* B_mo_own = own_rd[fpar ^ 1];

  // x-copy + ring-refill role: layer-0 wl==3 wave
  const bool xwave = (glay == 0) && (wl == 3);
  const bool xcopy = xwave && (lane < BPG * INSZ);
  const int cb = lane / INSZ, ck = lane % INSZ;
  const int rb = lane >> 5;
  const int rt = lane & 31;

  float cst = 0.0f;
  const float4_t fzc = {0.0f, 0.0f, 0.0f, 0.0f};
  float4_t a0 = fzc, a1 = fzc, a2 = fzc, a3 = fzc;  // persist across barriers

#define M_PHASE(PIN, POWN)                                                      \
  {                                                                             \
    if (glay == 0) {                                                            \
      const half8_t v0 = *(const half8_t*)(POWN);                               \
      const half8_t v1 = *(const half8_t*)((POWN) + 32);                        \
      if (wl != 3) {                                                            \
        a0 = MFMA16(afrag[0][0], v0, fzc); a1 = MFMA16(afrag[1][0], v0, fzc);   \
        a2 = MFMA16(afrag[2][0], v0, fzc); a3 = MFMA16(afrag[3][0], v0, fzc);   \
        a0 = MFMA16(afrag[0][1], v1, a0); a1 = MFMA16(afrag[1][1], v1, a1);     \
        a2 = MFMA16(afrag[2][1], v1, a2); a3 = MFMA16(afrag[3][1], v1, a3);     \
      } else {                                                                  \
        a0 = MFMA16(afrag[0][0], v0, fzc);                                      \
        a0 = MFMA16(afrag[0][1], v1, a0);                                       \
      }                                                                         \
    } else {                                                                    \
      const half8_t v0 = *(const half8_t*)(PIN);                                \
      const half8_t v1 = *(const half8_t*)((PIN) + 32);                         \
      const half8_t v2 = *(const half8_t*)(POWN);                               \
      const half8_t v3 = *(const half8_t*)((POWN) + 32);                        \
      if (wl != 3) {                                                            \
        a0 = MFMA16(afrag[0][0], v0, fzc); a1 = MFMA16(afrag[1][0], v0, fzc);   \
        a2 = MFMA16(afrag[2][0], v0, fzc); a3 = MFMA16(afrag[3][0], v0, fzc);   \
        a0 = MFMA16(afrag[0][1], v1, a0); a1 = MFMA16(afrag[1][1], v1, a1);     \
        a2 = MFMA16(afrag[2][1], v1, a2); a3 = MFMA16(afrag[3][1], v1, a3);     \
        a0 = MFMA16(afrag[0][2], v2, a0); a1 = MFMA16(afrag[1][2], v2, a1);     \
        a2 = MFMA16(afrag[2][2], v2, a2); a3 = MFMA16(afrag[3][2], v2, a3);     \
        a0 = MFMA16(afrag[0][3], v3, a0); a1 = MFMA16(afrag[1][3], v3, a1);     \
        a2 = MFMA16(afrag[2][3], v3, a2); a3 = MFMA16(afrag[3][3], v3, a3);     \
      } else {                                                                  \
        a0 = MFMA16(afrag[0][0], v0, fzc);                                      \
        a0 = MFMA16(afrag[0][1], v1, a0);                                       \
        a0 = MFMA16(afrag[0][2], v2, a0);                                       \
        a0 = MFMA16(afrag[0][3], v3, a0);                                       \
      }                                                                         \
    }                                                                           \
  }

#define U_PHASE(PST, FCW)                                                       \
  if (updact) {                                                                 \
    const float4_t g01 = (col & 4) ? a1 : a0;                                   \
    const float4_t g23 = (col & 4) ? a3 : a2;                                   \
    const float4_t ga = (col & 8) ? g23 : g01;                                  \
    const float di = 1.0f + EXP2F(-1.442695041f * ga[0]);                       \
    const float df = 1.0f + EXP2F(-1.442695041f * ga[1]);                       \
    const float dg = 1.0f + EXP2F(-2.885390082f * ga[2]);                       \
    const float dq = 1.0f + EXP2F(-1.442695041f * ga[3]);                       \
    const float r1 = RCPF(di * df);                                             \
    const float r2 = RCPF(dg * dq);                                             \
    const float gi = r1 * df;                                                   \
    const float gf = r1 * di;                                                   \
    const float gg = 2.0f * (r2 * dq) - 1.0f;                                   \
    const float go = r2 * dg;                                                   \
    cst = gf * cst + gi * gg;                                                   \
    const float dc = 1.0f + EXP2F(-2.885390082f * cst);                         \
    const float h = go * (2.0f * RCPF(dc) - 1.0f);                              \
    *(PST) = (half_t)h;                                                         \
    if (FCW) fc_h[bb][uu] = h;                                                  \
  }

  // x-copy: x(i+1) -> Xpack[i&1] slots 0..6 (runs in L0's update window)
#define XCOPY_RF(I)                                                             \
  if (xcopy && (I) < TT - 1) {                                                  \
    Xpack[(I) & 1][cb][ck] = Xstage[((I) + 1) & 63][cb][ck];                    \
  }                                                                             \
  if (xwave && ((I) & 31) == 8 && (I) < 480) {                                  \
    const int tb = ((I) & ~31) + 32;                                            \
    _Pragma("unroll")                                                           \
    for (int pp = 0; pp < 2; ++pp) {                                            \
      const int b = rb + 2 * pp;                                                \
      const int t = tb + rt;                                                    \
      const float* src = &p.x[((size_t)(b0 + b) * TT + t) * INSZ];              \
      half_t* dst = &Xstage[t & 63][b][0];                                      \
      _Pragma("unroll")                                                         \
      for (int k = 0; k < INSZ; ++k) dst[k] = (half_t)src[k];                   \
    }                                                                           \
  }

  // ---- prologue: i = 0..4 (guarded, dynamic parity) ----
  for (int i = 0; i < 5; ++i) {
    if (evl) {
      const int t = i - F;
      if (t >= 0) M_PHASE(in_rd[t & 1], own_rd[(t & 1) ^ 1])
    } else {
      const int tu = i - F;
      if (tu >= 0) U_PHASE(st[tu & 1], false)
    }
    __syncthreads();
    if (evl) {
      const int t = i - F;
      if (t >= 0) U_PHASE(st[t & 1], false)
    } else {
      const int tm = i - F + 1;
      if (tm >= 0) M_PHASE(in_rd[tm & 1], own_rd[(tm & 1) ^ 1])
    }
    XCOPY_RF(i)
    __syncthreads();
  }

  // ---- steady: i = 5..510, unrolled x2 (i odd then even), no guards ----
  for (int i = 5; i < 511; i += 2) {
    // iteration i (odd: PAR = fpar^1 -> B-set)
    if (evl) M_PHASE(B_m_in, B_m_own)
    else U_PHASE(B_st, false)
    __syncthreads();
    if (evl) U_PHASE(B_st, false)
    else M_PHASE(B_mo_in, B_mo_own)
    XCOPY_RF(i)
    __syncthreads();
    // iteration i+1 (even: PAR = fpar -> A-set)
    if (evl) M_PHASE(A_m_in, A_m_own)
    else U_PHASE(A_st, false)
    __syncthreads();
    if (evl) U_PHASE(A_st, false)
    else M_PHASE(A_mo_in, A_mo_own)
    XCOPY_RF(i + 1)
    __syncthreads();
  }

  // ---- tail: i = 511..516 (guarded; FC write at L3 update t=511) ----
  for (int i = 511; i < 517; ++i) {
    if (evl) {
      const int t = i - F;
      if (t <= TT - 1) M_PHASE(in_rd[t & 1], own_rd[(t & 1) ^ 1])
    } else {
      const int tu = i - F;
      if (tu <= TT - 1) U_PHASE(st[tu & 1], (glay == 3) && (tu == TT - 1))
    }
    __syncthreads();
    if (evl) {
      const int t = i - F;
      if (t <= TT - 1) U_PHASE(st[t & 1], false)
    } else {
      const int tm = i - F + 1;
      if (tm <= TT - 1) M_PHASE(in_rd[tm & 1], own_rd[(tm & 1) ^ 1])
    }
    __syncthreads();
  }

  // ---- FC head (fp32) ----
  if (tid < BPG * FC1N) {
    const int b = tid / FC1N, j = tid % FC1N;
    const float* w = p.W1 + j * H;
    float a = p.b1[j];
#pragma unroll
    for (int k = 0; k < H; ++k) a += fc_h[b][k] * w[k];
    fc1_buf[b][j] = fmaxf(a, 0.0f);
  }
  __syncthreads();
  if (tid < BPG) {
    float a = p.b2[0];
#pragma unroll
    for (int j = 0; j < FC1N; ++j) a += fc1_buf[tid][j] * p.W2[j];
    p.out[b0 + tid] = a;
  }
}

extern "C" void kernel_launch(void* const* d_in, const int* in_sizes, int n_in,
                              void* d_out, int out_size, void* d_ws, size_t ws_size,
                              hipStream_t stream) {
  Params p;
  p.x = (const float*)d_in[0];
  for (int l = 0; l < NL; ++l) {
    p.Wih[l] = (const float*)d_in[1 + 4 * l];
    p.Whh[l] = (const float*)d_in[2 + 4 * l];
    p.bih[l] = (const float*)d_in[3 + 4 * l];
    p.bhh[l] = (const float*)d_in[4 + 4 * l];
  }
  p.W1 = (const float*)d_in[17];
  p.b1 = (const float*)d_in[18];
  p.W2 = (const float*)d_in[19];
  p.b2 = (const float*)d_in[20];
  p.out = (float*)d_out;

  hipLaunchKernelGGL(lstm_r9, dim3(NBLK), dim3(NTHREADS), 0, stream, p);
}